// Round 1
// baseline (636.198 us; speedup 1.0000x reference)
//
#include <hip/hip_runtime.h>
#include <hip/hip_bf16.h>
#include <stdint.h>

// ---------- bf16 helpers (raw-bits; RNE pack) ----------
static __device__ __forceinline__ float bflo(uint32_t h){ return __uint_as_float(h << 16); }
static __device__ __forceinline__ float bfhi(uint32_t h){ return __uint_as_float(h & 0xFFFF0000u); }
static __device__ __forceinline__ uint32_t f2bf_bits(float f){
  uint32_t u = __float_as_uint(f);
  return (u + 0x7FFFu + ((u >> 16) & 1u)) >> 16;
}
static __device__ __forceinline__ uint32_t pack2bf(float lo, float hi){
  return f2bf_bits(lo) | (f2bf_bits(hi) << 16);
}

// ---------- graph build ----------
__global__ __launch_bounds__(256) void k_count(const int* __restrict__ dst, int E,
                                               int* __restrict__ cnt){
  int e = blockIdx.x * 256 + threadIdx.x;
  if (e < E) atomicAdd(&cnt[dst[e]], 1);
}

// dinv[i] = rsqrt(cnt[i]+1)  (self-loop), start[i] = running offset (order-free CSR)
__global__ __launch_bounds__(256) void k_dinv_start(const int* __restrict__ cnt,
    float* __restrict__ dinv, int* __restrict__ start, int* __restrict__ counter, int n){
  int i = blockIdx.x * 256 + threadIdx.x;
  int lane = threadIdx.x & 63;
  int c = (i < n) ? cnt[i] : 0;
  if (i < n) dinv[i] = rsqrtf((float)(c + 1));
  int pref = c;
  #pragma unroll
  for (int off = 1; off < 64; off <<= 1){
    int v = __shfl_up(pref, off);
    if (lane >= off) pref += v;
  }
  int total = __shfl(pref, 63);
  int base = 0;
  if (lane == 63) base = atomicAdd(counter, total);
  base = __shfl(base, 63);
  if (i < n) start[i] = base + pref - c;
}

__global__ __launch_bounds__(256) void k_fill(const int* __restrict__ src,
    const int* __restrict__ dst, int E, const float* __restrict__ dinv,
    const int* __restrict__ start, int* __restrict__ fillpos,
    int* __restrict__ csr, float* __restrict__ csrw){
  int e = blockIdx.x * 256 + threadIdx.x;
  if (e < E){
    int s = src[e], d = dst[e];
    int p = atomicAdd(&fillpos[d], 1);
    int idx = start[d] + p;
    csr[idx] = s;
    csrw[idx] = dinv[s] * dinv[d];
  }
}

// ---------- GEMM1: H1[N,128](bf16) = X[N,256](f32) @ W1[256,128](f32) ----------
__global__ __launch_bounds__(256) void k_gemm1(const float* __restrict__ X,
    const float* __restrict__ W, uint32_t* __restrict__ H1, int n){
  __shared__ float xs[64][64];
  __shared__ float ws[64][128];
  int tid = threadIdx.x;
  int row0 = blockIdx.x * 64;
  int tx = tid & 31, ty = tid >> 5;
  float acc[8][4];
  #pragma unroll
  for (int r = 0; r < 8; ++r){ acc[r][0]=acc[r][1]=acc[r][2]=acc[r][3]=0.f; }
  for (int kt = 0; kt < 4; ++kt){
    #pragma unroll
    for (int i = 0; i < 4; ++i){
      int lid = tid + i*256;
      int r = lid >> 4, c = (lid & 15) * 4;
      float4 v = make_float4(0.f,0.f,0.f,0.f);
      int gr = row0 + r;
      if (gr < n) v = *(const float4*)&X[(size_t)gr*256 + kt*64 + c];
      *(float4*)&xs[r][c] = v;
    }
    #pragma unroll
    for (int i = 0; i < 8; ++i){
      int lid = tid + i*256;
      int r = lid >> 5, c = (lid & 31) * 4;
      *(float4*)&ws[r][c] = *(const float4*)&W[(kt*64 + r)*128 + c];
    }
    __syncthreads();
    #pragma unroll 4
    for (int kk = 0; kk < 64; ++kk){
      float4 b = *(float4*)&ws[kk][tx*4];
      #pragma unroll
      for (int r = 0; r < 8; ++r){
        float a = xs[ty*8 + r][kk];
        acc[r][0] = fmaf(a, b.x, acc[r][0]);
        acc[r][1] = fmaf(a, b.y, acc[r][1]);
        acc[r][2] = fmaf(a, b.z, acc[r][2]);
        acc[r][3] = fmaf(a, b.w, acc[r][3]);
      }
    }
    __syncthreads();
  }
  #pragma unroll
  for (int r = 0; r < 8; ++r){
    int gr = row0 + ty*8 + r;
    if (gr < n){
      uint2 v;
      v.x = pack2bf(acc[r][0], acc[r][1]);
      v.y = pack2bf(acc[r][2], acc[r][3]);
      *(uint2*)&H1[(size_t)gr*64 + tx*2] = v;
    }
  }
}

// ---------- agg1: A1 = leakyrelu(Ahat @ H1 + b1)  (bf16 out) ----------
// one wave per node; lane covers 2 of 128 feature dims
__global__ __launch_bounds__(256) void k_agg1(const uint32_t* __restrict__ H1,
    const int* __restrict__ csr, const float* __restrict__ csrw,
    const int* __restrict__ start, const int* __restrict__ cnt,
    const float* __restrict__ dinv, const float* __restrict__ b1,
    uint32_t* __restrict__ A1, int n){
  int w = (int)((blockIdx.x * blockDim.x + threadIdx.x) >> 6);
  int lane = threadIdx.x & 63;
  if (w >= n) return;
  float di = dinv[w];
  uint32_t h = H1[(size_t)w*64 + lane];
  float sw = di * di;                 // self-loop weight
  float a0 = sw * bflo(h), a1 = sw * bfhi(h);
  int e0 = start[w], e1 = e0 + cnt[w];
  for (int e = e0; e < e1; ++e){
    int s = csr[e];
    float wt = csrw[e];
    uint32_t hh = H1[(size_t)s*64 + lane];
    a0 = fmaf(wt, bflo(hh), a0);
    a1 = fmaf(wt, bfhi(hh), a1);
  }
  a0 += b1[lane*2]; a1 += b1[lane*2+1];
  a0 = (a0 >= 0.f) ? a0 : 0.01f * a0;
  a1 = (a1 >= 0.f) ? a1 : 0.01f * a1;
  A1[(size_t)w*64 + lane] = pack2bf(a0, a1);
}

// ---------- GEMM2: H2[N,64](bf16) = A1[N,128](bf16) @ W2[128,64](f32) ----------
__global__ __launch_bounds__(256) void k_gemm2(const uint32_t* __restrict__ A1,
    const float* __restrict__ W2, uint32_t* __restrict__ H2, int n){
  __shared__ unsigned short as2[64][136];  // +8 pad: breaks 4-way bank alias on a-reads
  __shared__ float w2s[128][64];
  int tid = threadIdx.x;
  int row0 = blockIdx.x * 64;
  #pragma unroll
  for (int i = 0; i < 8; ++i){
    int lid = tid + i*256;
    int r = lid >> 4, c = (lid & 15) * 4;
    *(float4*)&w2s[r][c] = *(const float4*)&W2[r*64 + c];
  }
  #pragma unroll
  for (int i = 0; i < 4; ++i){
    int lid = tid + i*256;
    int r = lid >> 4, cu = (lid & 15) * 4;
    uint4 v = make_uint4(0,0,0,0);
    int gr = row0 + r;
    if (gr < n) v = *(const uint4*)&A1[(size_t)gr*64 + cu];
    *(uint4*)&as2[r][cu*2] = v;
  }
  __syncthreads();
  int tx = tid & 15, ty = tid >> 4;
  float acc[4][4];
  #pragma unroll
  for (int r = 0; r < 4; ++r){ acc[r][0]=acc[r][1]=acc[r][2]=acc[r][3]=0.f; }
  #pragma unroll 4
  for (int kk = 0; kk < 128; ++kk){
    float4 b = *(float4*)&w2s[kk][tx*4];
    #pragma unroll
    for (int r = 0; r < 4; ++r){
      float a = __uint_as_float(((uint32_t)as2[ty*4 + r][kk]) << 16);
      acc[r][0] = fmaf(a, b.x, acc[r][0]);
      acc[r][1] = fmaf(a, b.y, acc[r][1]);
      acc[r][2] = fmaf(a, b.z, acc[r][2]);
      acc[r][3] = fmaf(a, b.w, acc[r][3]);
    }
  }
  #pragma unroll
  for (int r = 0; r < 4; ++r){
    int gr = row0 + ty*4 + r;
    if (gr < n){
      uint2 v;
      v.x = pack2bf(acc[r][0], acc[r][1]);
      v.y = pack2bf(acc[r][2], acc[r][3]);
      *(uint2*)&H2[(size_t)gr*32 + tx*2] = v;
    }
  }
}

// ---------- agg2: out = Ahat @ H2 + b2  (f32 out) ----------
// one wave per node; lane covers 1 of 64 feature dims
__global__ __launch_bounds__(256) void k_agg2(const unsigned short* __restrict__ H2,
    const int* __restrict__ csr, const float* __restrict__ csrw,
    const int* __restrict__ start, const int* __restrict__ cnt,
    const float* __restrict__ dinv, const float* __restrict__ b2,
    float* __restrict__ out, int n){
  int w = (int)((blockIdx.x * blockDim.x + threadIdx.x) >> 6);
  int lane = threadIdx.x & 63;
  if (w >= n) return;
  float di = dinv[w];
  float a = di * di * __uint_as_float(((uint32_t)H2[(size_t)w*64 + lane]) << 16);
  int e0 = start[w], e1 = e0 + cnt[w];
  for (int e = e0; e < e1; ++e){
    int s = csr[e];
    float wt = csrw[e];
    a = fmaf(wt, __uint_as_float(((uint32_t)H2[(size_t)s*64 + lane]) << 16), a);
  }
  out[(size_t)w*64 + lane] = a + b2[lane];
}

extern "C" void kernel_launch(void* const* d_in, const int* in_sizes, int n_in,
                              void* d_out, int out_size, void* d_ws, size_t ws_size,
                              hipStream_t stream){
  const float* x  = (const float*)d_in[0];
  const int*   ei = (const int*)d_in[1];   // [2,E] int32 (harness converts integer inputs)
  const float* W1 = (const float*)d_in[2];
  const float* b1 = (const float*)d_in[3];
  const float* W2 = (const float*)d_in[4];
  const float* b2 = (const float*)d_in[5];
  float* out = (float*)d_out;

  int N = in_sizes[0] / 256;
  int E = in_sizes[1] / 2;

  char* p = (char*)d_ws;
  uint32_t* H1 = (uint32_t*)p;  p += (size_t)N*64*4;   // [N,128] bf16
  uint32_t* A1 = (uint32_t*)p;  p += (size_t)N*64*4;   // [N,128] bf16
  uint32_t* H2 = (uint32_t*)p;  p += (size_t)N*32*4;   // [N,64]  bf16
  int* csr     = (int*)p;       p += (size_t)E*4;
  float* csrw  = (float*)p;     p += (size_t)E*4;
  int* cnt     = (int*)p;       p += (size_t)N*4;      // | contiguous zero region:
  int* fillpos = (int*)p;       p += (size_t)N*4;      // | cnt, fillpos, counter
  int* counter = (int*)p;       p += 16;               // |
  int* start   = (int*)p;       p += (size_t)N*4;
  float* dinv  = (float*)p;     p += (size_t)N*4;

  hipMemsetAsync(cnt, 0, (size_t)(2*N)*4 + 16, stream);

  const int* srcIdx = ei;
  const int* dstIdx = ei + E;

  k_count<<<(E+255)/256, 256, 0, stream>>>(dstIdx, E, cnt);
  k_dinv_start<<<(N+255)/256, 256, 0, stream>>>(cnt, dinv, start, counter, N);
  k_fill<<<(E+255)/256, 256, 0, stream>>>(srcIdx, dstIdx, E, dinv, start, fillpos, csr, csrw);
  k_gemm1<<<(N+63)/64, 256, 0, stream>>>(x, W1, H1, N);
  k_agg1<<<(N+3)/4, 256, 0, stream>>>(H1, csr, csrw, start, cnt, dinv, b1, A1, N);
  k_gemm2<<<(N+63)/64, 256, 0, stream>>>(A1, W2, H2, N);
  k_agg2<<<(N+3)/4, 256, 0, stream>>>((const unsigned short*)H2, csr, csrw, start, cnt, dinv, b2, out, N);
}

// Round 2
// 409.949 us; speedup vs baseline: 1.5519x; 1.5519x over previous
//
#include <hip/hip_runtime.h>
#include <hip/hip_bf16.h>
#include <stdint.h>

// ---------- bf16 helpers (raw-bits; RNE pack) ----------
static __device__ __forceinline__ float bflo(uint32_t h){ return __uint_as_float(h << 16); }
static __device__ __forceinline__ float bfhi(uint32_t h){ return __uint_as_float(h & 0xFFFF0000u); }
static __device__ __forceinline__ uint32_t f2bf_bits(float f){
  uint32_t u = __float_as_uint(f);
  return (u + 0x7FFFu + ((u >> 16) & 1u)) >> 16;
}
static __device__ __forceinline__ uint32_t pack2bf(float lo, float hi){
  return f2bf_bits(lo) | (f2bf_bits(hi) << 16);
}

// ---------- graph build ----------
__global__ __launch_bounds__(256) void k_count(const int* __restrict__ dst, int E,
                                               int* __restrict__ cnt){
  int e = blockIdx.x * 256 + threadIdx.x;
  if (e < E) atomicAdd(&cnt[dst[e]], 1);
}

// dinv[i] = rsqrt(cnt[i]+1)  (self-loop), start[i] = running offset (order-free CSR)
__global__ __launch_bounds__(256) void k_dinv_start(const int* __restrict__ cnt,
    float* __restrict__ dinv, int* __restrict__ start, int* __restrict__ counter, int n){
  int i = blockIdx.x * 256 + threadIdx.x;
  int lane = threadIdx.x & 63;
  int c = (i < n) ? cnt[i] : 0;
  if (i < n) dinv[i] = rsqrtf((float)(c + 1));
  int pref = c;
  #pragma unroll
  for (int off = 1; off < 64; off <<= 1){
    int v = __shfl_up(pref, off);
    if (lane >= off) pref += v;
  }
  int total = __shfl(pref, 63);
  int base = 0;
  if (lane == 63) base = atomicAdd(counter, total);
  base = __shfl(base, 63);
  if (i < n) start[i] = base + pref - c;
}

// packed edge list: edges[idx] = (src, bits(dinv[src]*dinv[dst]))
__global__ __launch_bounds__(256) void k_fill(const int* __restrict__ src,
    const int* __restrict__ dst, int E, const float* __restrict__ dinv,
    const int* __restrict__ start, int* __restrict__ fillpos,
    int2* __restrict__ edges){
  int e = blockIdx.x * 256 + threadIdx.x;
  if (e < E){
    int s = src[e], d = dst[e];
    int p = atomicAdd(&fillpos[d], 1);
    int idx = start[d] + p;
    edges[idx] = make_int2(s, __float_as_int(dinv[s] * dinv[d]));
  }
}

// ---------- GEMM1: H1[N,128](bf16) = X[N,256](f32) @ W1[256,128](f32) ----------
__global__ __launch_bounds__(256) void k_gemm1(const float* __restrict__ X,
    const float* __restrict__ W, uint32_t* __restrict__ H1, int n){
  __shared__ float xs[64][64];
  __shared__ float ws[64][128];
  int tid = threadIdx.x;
  int row0 = blockIdx.x * 64;
  int tx = tid & 31, ty = tid >> 5;
  float acc[8][4];
  #pragma unroll
  for (int r = 0; r < 8; ++r){ acc[r][0]=acc[r][1]=acc[r][2]=acc[r][3]=0.f; }
  for (int kt = 0; kt < 4; ++kt){
    #pragma unroll
    for (int i = 0; i < 4; ++i){
      int lid = tid + i*256;
      int r = lid >> 4, c = (lid & 15) * 4;
      float4 v = make_float4(0.f,0.f,0.f,0.f);
      int gr = row0 + r;
      if (gr < n) v = *(const float4*)&X[(size_t)gr*256 + kt*64 + c];
      *(float4*)&xs[r][c] = v;
    }
    #pragma unroll
    for (int i = 0; i < 8; ++i){
      int lid = tid + i*256;
      int r = lid >> 5, c = (lid & 31) * 4;
      *(float4*)&ws[r][c] = *(const float4*)&W[(kt*64 + r)*128 + c];
    }
    __syncthreads();
    #pragma unroll 4
    for (int kk = 0; kk < 64; ++kk){
      float4 b = *(float4*)&ws[kk][tx*4];
      #pragma unroll
      for (int r = 0; r < 8; ++r){
        float a = xs[ty*8 + r][kk];
        acc[r][0] = fmaf(a, b.x, acc[r][0]);
        acc[r][1] = fmaf(a, b.y, acc[r][1]);
        acc[r][2] = fmaf(a, b.z, acc[r][2]);
        acc[r][3] = fmaf(a, b.w, acc[r][3]);
      }
    }
    __syncthreads();
  }
  #pragma unroll
  for (int r = 0; r < 8; ++r){
    int gr = row0 + ty*8 + r;
    if (gr < n){
      uint2 v;
      v.x = pack2bf(acc[r][0], acc[r][1]);
      v.y = pack2bf(acc[r][2], acc[r][3]);
      *(uint2*)&H1[(size_t)gr*64 + tx*2] = v;
    }
  }
}

// ---------- agg1: A1 = leakyrelu(Ahat @ H1 + b1)  (bf16 out) ----------
// one wave per node; lane covers 2 of 128 feature dims.
// Edge (src,w) pairs are loaded cooperatively (one coalesced int2 per lane),
// broadcast via shfl; gathers unrolled x8 for MLP.
__global__ __launch_bounds__(256) void k_agg1(const uint32_t* __restrict__ H1,
    const int2* __restrict__ edges,
    const int* __restrict__ start, const int* __restrict__ cnt,
    const float* __restrict__ dinv, const float* __restrict__ b1,
    uint32_t* __restrict__ A1, int n){
  int w = (int)((blockIdx.x * blockDim.x + threadIdx.x) >> 6);
  int lane = threadIdx.x & 63;
  if (w >= n) return;
  float di = dinv[w];
  uint32_t h = H1[(size_t)w*64 + lane];
  float sw = di * di;                 // self-loop weight
  float a0 = sw * bflo(h), a1 = sw * bfhi(h);
  int e0 = start[w], deg = cnt[w];
  for (int base = 0; base < deg; base += 64){
    int nin = min(64, deg - base);
    int2 ew = (lane < nin) ? edges[e0 + base + lane] : make_int2(0, 0);
    for (int j = 0; j < nin; j += 8){
      int ss[8]; float wts[8];
      #pragma unroll
      for (int u = 0; u < 8; ++u){
        int jj = j + u;
        int s = __shfl(ew.x, jj & 63);
        uint32_t wb = (uint32_t)__shfl(ew.y, jj & 63);
        bool ok = jj < nin;
        ss[u] = ok ? s : w;
        wts[u] = ok ? __uint_as_float(wb) : 0.f;
      }
      uint32_t hh[8];
      #pragma unroll
      for (int u = 0; u < 8; ++u) hh[u] = H1[(size_t)ss[u]*64 + lane];
      #pragma unroll
      for (int u = 0; u < 8; ++u){
        a0 = fmaf(wts[u], bflo(hh[u]), a0);
        a1 = fmaf(wts[u], bfhi(hh[u]), a1);
      }
    }
  }
  a0 += b1[lane*2]; a1 += b1[lane*2+1];
  a0 = (a0 >= 0.f) ? a0 : 0.01f * a0;
  a1 = (a1 >= 0.f) ? a1 : 0.01f * a1;
  A1[(size_t)w*64 + lane] = pack2bf(a0, a1);
}

// ---------- GEMM2: H2[N,64](bf16) = A1[N,128](bf16) @ W2[128,64](f32) ----------
__global__ __launch_bounds__(256) void k_gemm2(const uint32_t* __restrict__ A1,
    const float* __restrict__ W2, uint32_t* __restrict__ H2, int n){
  __shared__ unsigned short as2[64][136];  // +8 pad: breaks 4-way bank alias on a-reads
  __shared__ float w2s[128][64];
  int tid = threadIdx.x;
  int row0 = blockIdx.x * 64;
  #pragma unroll
  for (int i = 0; i < 8; ++i){
    int lid = tid + i*256;
    int r = lid >> 4, c = (lid & 15) * 4;
    *(float4*)&w2s[r][c] = *(const float4*)&W2[r*64 + c];
  }
  #pragma unroll
  for (int i = 0; i < 4; ++i){
    int lid = tid + i*256;
    int r = lid >> 4, cu = (lid & 15) * 4;
    uint4 v = make_uint4(0,0,0,0);
    int gr = row0 + r;
    if (gr < n) v = *(const uint4*)&A1[(size_t)gr*64 + cu];
    *(uint4*)&as2[r][cu*2] = v;
  }
  __syncthreads();
  int tx = tid & 15, ty = tid >> 4;
  float acc[4][4];
  #pragma unroll
  for (int r = 0; r < 4; ++r){ acc[r][0]=acc[r][1]=acc[r][2]=acc[r][3]=0.f; }
  #pragma unroll 4
  for (int kk = 0; kk < 128; ++kk){
    float4 b = *(float4*)&w2s[kk][tx*4];
    #pragma unroll
    for (int r = 0; r < 4; ++r){
      float a = __uint_as_float(((uint32_t)as2[ty*4 + r][kk]) << 16);
      acc[r][0] = fmaf(a, b.x, acc[r][0]);
      acc[r][1] = fmaf(a, b.y, acc[r][1]);
      acc[r][2] = fmaf(a, b.z, acc[r][2]);
      acc[r][3] = fmaf(a, b.w, acc[r][3]);
    }
  }
  #pragma unroll
  for (int r = 0; r < 4; ++r){
    int gr = row0 + ty*4 + r;
    if (gr < n){
      uint2 v;
      v.x = pack2bf(acc[r][0], acc[r][1]);
      v.y = pack2bf(acc[r][2], acc[r][3]);
      *(uint2*)&H2[(size_t)gr*32 + tx*2] = v;
    }
  }
}

// ---------- agg2: out = Ahat @ H2 + b2  (f32 out) ----------
// one wave per node; lane covers 1 of 64 feature dims
__global__ __launch_bounds__(256) void k_agg2(const unsigned short* __restrict__ H2,
    const int2* __restrict__ edges,
    const int* __restrict__ start, const int* __restrict__ cnt,
    const float* __restrict__ dinv, const float* __restrict__ b2,
    float* __restrict__ out, int n){
  int w = (int)((blockIdx.x * blockDim.x + threadIdx.x) >> 6);
  int lane = threadIdx.x & 63;
  if (w >= n) return;
  float di = dinv[w];
  float a = di * di * __uint_as_float(((uint32_t)H2[(size_t)w*64 + lane]) << 16);
  int e0 = start[w], deg = cnt[w];
  for (int base = 0; base < deg; base += 64){
    int nin = min(64, deg - base);
    int2 ew = (lane < nin) ? edges[e0 + base + lane] : make_int2(0, 0);
    for (int j = 0; j < nin; j += 8){
      int ss[8]; float wts[8];
      #pragma unroll
      for (int u = 0; u < 8; ++u){
        int jj = j + u;
        int s = __shfl(ew.x, jj & 63);
        uint32_t wb = (uint32_t)__shfl(ew.y, jj & 63);
        bool ok = jj < nin;
        ss[u] = ok ? s : w;
        wts[u] = ok ? __uint_as_float(wb) : 0.f;
      }
      unsigned short hh[8];
      #pragma unroll
      for (int u = 0; u < 8; ++u) hh[u] = H2[(size_t)ss[u]*64 + lane];
      #pragma unroll
      for (int u = 0; u < 8; ++u)
        a = fmaf(wts[u], __uint_as_float(((uint32_t)hh[u]) << 16), a);
    }
  }
  out[(size_t)w*64 + lane] = a + b2[lane];
}

extern "C" void kernel_launch(void* const* d_in, const int* in_sizes, int n_in,
                              void* d_out, int out_size, void* d_ws, size_t ws_size,
                              hipStream_t stream){
  const float* x  = (const float*)d_in[0];
  const int*   ei = (const int*)d_in[1];   // [2,E] int32
  const float* W1 = (const float*)d_in[2];
  const float* b1 = (const float*)d_in[3];
  const float* W2 = (const float*)d_in[4];
  const float* b2 = (const float*)d_in[5];
  float* out = (float*)d_out;

  int N = in_sizes[0] / 256;
  int E = in_sizes[1] / 2;

  char* p = (char*)d_ws;
  uint32_t* H1 = (uint32_t*)p;  p += (size_t)N*64*4;   // [N,128] bf16
  uint32_t* A1 = (uint32_t*)p;  p += (size_t)N*64*4;   // [N,128] bf16
  uint32_t* H2 = (uint32_t*)p;  p += (size_t)N*32*4;   // [N,64]  bf16
  int2* edges  = (int2*)p;      p += (size_t)E*8;      // packed (src, w)
  int* cnt     = (int*)p;       p += (size_t)N*4;      // | contiguous zero region:
  int* fillpos = (int*)p;       p += (size_t)N*4;      // | cnt, fillpos, counter
  int* counter = (int*)p;       p += 16;               // |
  int* start   = (int*)p;       p += (size_t)N*4;
  float* dinv  = (float*)p;     p += (size_t)N*4;

  hipMemsetAsync(cnt, 0, (size_t)(2*N)*4 + 16, stream);

  const int* srcIdx = ei;
  const int* dstIdx = ei + E;

  k_count<<<(E+255)/256, 256, 0, stream>>>(dstIdx, E, cnt);
  k_dinv_start<<<(N+255)/256, 256, 0, stream>>>(cnt, dinv, start, counter, N);
  k_fill<<<(E+255)/256, 256, 0, stream>>>(srcIdx, dstIdx, E, dinv, start, fillpos, edges);
  k_gemm1<<<(N+63)/64, 256, 0, stream>>>(x, W1, H1, N);
  k_agg1<<<(N+3)/4, 256, 0, stream>>>(H1, edges, start, cnt, dinv, b1, A1, N);
  k_gemm2<<<(N+63)/64, 256, 0, stream>>>(A1, W2, H2, N);
  k_agg2<<<(N+3)/4, 256, 0, stream>>>((const unsigned short*)H2, edges, start, cnt, dinv, b2, out, N);
}

// Round 3
// 354.747 us; speedup vs baseline: 1.7934x; 1.1556x over previous
//
#include <hip/hip_runtime.h>
#include <hip/hip_bf16.h>
#include <stdint.h>

typedef short short8 __attribute__((ext_vector_type(8)));
typedef float f32x4 __attribute__((ext_vector_type(4)));
union U4S8 { uint4 u; short8 s; };

// ---------- bf16 helpers (raw-bits; RNE pack) ----------
static __device__ __forceinline__ float bflo(uint32_t h){ return __uint_as_float(h << 16); }
static __device__ __forceinline__ float bfhi(uint32_t h){ return __uint_as_float(h & 0xFFFF0000u); }
static __device__ __forceinline__ uint32_t f2bf_bits(float f){
  uint32_t u = __float_as_uint(f);
  return (u + 0x7FFFu + ((u >> 16) & 1u)) >> 16;
}
static __device__ __forceinline__ uint32_t pack2bf(float lo, float hi){
  return f2bf_bits(lo) | (f2bf_bits(hi) << 16);
}

// ---------- graph build ----------
__global__ __launch_bounds__(256) void k_count(const int* __restrict__ dst, int E,
                                               int* __restrict__ cnt){
  int e = blockIdx.x * 256 + threadIdx.x;
  if (e < E) atomicAdd(&cnt[dst[e]], 1);
}

__global__ __launch_bounds__(256) void k_dinv_start(const int* __restrict__ cnt,
    float* __restrict__ dinv, int* __restrict__ start, int* __restrict__ counter, int n){
  int i = blockIdx.x * 256 + threadIdx.x;
  int lane = threadIdx.x & 63;
  int c = (i < n) ? cnt[i] : 0;
  if (i < n) dinv[i] = rsqrtf((float)(c + 1));
  int pref = c;
  #pragma unroll
  for (int off = 1; off < 64; off <<= 1){
    int v = __shfl_up(pref, off);
    if (lane >= off) pref += v;
  }
  int total = __shfl(pref, 63);
  int base = 0;
  if (lane == 63) base = atomicAdd(counter, total);
  base = __shfl(base, 63);
  if (i < n) start[i] = base + pref - c;
}

// packed edge list: edges[idx] = (src, bits(dinv[src]*dinv[dst]))
__global__ __launch_bounds__(256) void k_fill(const int* __restrict__ src,
    const int* __restrict__ dst, int E, const float* __restrict__ dinv,
    const int* __restrict__ start, int* __restrict__ fillpos,
    int2* __restrict__ edges){
  int e = blockIdx.x * 256 + threadIdx.x;
  if (e < E){
    int s = src[e], d = dst[e];
    int p = atomicAdd(&fillpos[d], 1);
    int idx = start[d] + p;
    edges[idx] = make_int2(s, __float_as_int(dinv[s] * dinv[d]));
  }
}

// ---------- weight pre-pack: W[K][Nc] f32 -> bf16 MFMA B-fragments ----------
// Wf slot s = (ks*NT + nt)*64 + lane holds B[k0..k0+8)[col] where
// col = nt*16 + (lane&15), k0 = ks*32 + (lane>>4)*8.
__global__ __launch_bounds__(256) void k_packW(const float* __restrict__ W,
    uint4* __restrict__ Wf, int K, int Nc){
  int s = blockIdx.x * 256 + threadIdx.x;
  int total = (K >> 5) * (Nc >> 4) * 64;
  if (s >= total) return;
  int lane = s & 63;
  int frag = s >> 6;
  int NT = Nc >> 4;
  int nt = frag % NT, ks = frag / NT;
  int col = nt*16 + (lane & 15);
  int k0  = ks*32 + (lane >> 4)*8;
  float v[8];
  #pragma unroll
  for (int e = 0; e < 8; ++e) v[e] = W[(size_t)(k0 + e)*Nc + col];
  uint4 u;
  u.x = pack2bf(v[0], v[1]); u.y = pack2bf(v[2], v[3]);
  u.z = pack2bf(v[4], v[5]); u.w = pack2bf(v[6], v[7]);
  Wf[s] = u;
}

// ---------- GEMM1 (MFMA): H1[N,128](bf16) = bf16(X[N,256]) @ bf16(W1) ----------
// one wave per 32 rows; LDS-free; A-frags converted in-register.
__global__ __launch_bounds__(256) void k_gemm1_mfma(const float* __restrict__ X,
    const uint4* __restrict__ W1f, unsigned short* __restrict__ H1, int n){
  int wv = (int)((blockIdx.x * 256u + threadIdx.x) >> 6);
  int lane = threadIdx.x & 63;
  int row0 = wv * 32;
  if (row0 >= n) return;
  int rA = lane & 15, kg = lane >> 4;
  f32x4 acc[2][8];
  #pragma unroll
  for (int mt = 0; mt < 2; ++mt)
    #pragma unroll
    for (int nt = 0; nt < 8; ++nt) acc[mt][nt] = (f32x4){0.f, 0.f, 0.f, 0.f};
  int r0 = min(row0 + rA,      n - 1);
  int r1 = min(row0 + 16 + rA, n - 1);
  const float* x0 = X + (size_t)r0*256 + kg*8;
  const float* x1 = X + (size_t)r1*256 + kg*8;
  for (int ks = 0; ks < 8; ++ks){
    U4S8 a0, a1; float4 f;
    f = *(const float4*)(x0 + ks*32);     a0.u.x = pack2bf(f.x,f.y); a0.u.y = pack2bf(f.z,f.w);
    f = *(const float4*)(x0 + ks*32 + 4); a0.u.z = pack2bf(f.x,f.y); a0.u.w = pack2bf(f.z,f.w);
    f = *(const float4*)(x1 + ks*32);     a1.u.x = pack2bf(f.x,f.y); a1.u.y = pack2bf(f.z,f.w);
    f = *(const float4*)(x1 + ks*32 + 4); a1.u.z = pack2bf(f.x,f.y); a1.u.w = pack2bf(f.z,f.w);
    #pragma unroll
    for (int nt = 0; nt < 8; ++nt){
      U4S8 b; b.u = W1f[(ks*8 + nt)*64 + lane];
      acc[0][nt] = __builtin_amdgcn_mfma_f32_16x16x32_bf16(a0.s, b.s, acc[0][nt], 0, 0, 0);
      acc[1][nt] = __builtin_amdgcn_mfma_f32_16x16x32_bf16(a1.s, b.s, acc[1][nt], 0, 0, 0);
    }
  }
  #pragma unroll
  for (int mt = 0; mt < 2; ++mt){
    #pragma unroll
    for (int r = 0; r < 4; ++r){
      int row = row0 + mt*16 + kg*4 + r;
      if (row < n){
        #pragma unroll
        for (int nt = 0; nt < 8; ++nt)
          H1[(size_t)row*128 + nt*16 + rA] = (unsigned short)f2bf_bits(acc[mt][nt][r]);
      }
    }
  }
}

// ---------- agg1: A1 = leakyrelu(Ahat @ H1 + b1)  (bf16 out) ----------
__global__ __launch_bounds__(256) void k_agg1(const uint32_t* __restrict__ H1,
    const int2* __restrict__ edges,
    const int* __restrict__ start, const int* __restrict__ cnt,
    const float* __restrict__ dinv, const float* __restrict__ b1,
    uint32_t* __restrict__ A1, int n){
  int w = (int)((blockIdx.x * blockDim.x + threadIdx.x) >> 6);
  int lane = threadIdx.x & 63;
  if (w >= n) return;
  float di = dinv[w];
  uint32_t h = H1[(size_t)w*64 + lane];
  float sw = di * di;                 // self-loop weight
  float a0 = sw * bflo(h), a1 = sw * bfhi(h);
  int e0 = start[w], deg = cnt[w];
  for (int base = 0; base < deg; base += 64){
    int nin = min(64, deg - base);
    int2 ew = (lane < nin) ? edges[e0 + base + lane] : make_int2(0, 0);
    for (int j = 0; j < nin; j += 8){
      int ss[8]; float wts[8];
      #pragma unroll
      for (int u = 0; u < 8; ++u){
        int jj = j + u;
        int s = __shfl(ew.x, jj & 63);
        uint32_t wb = (uint32_t)__shfl(ew.y, jj & 63);
        bool ok = jj < nin;
        ss[u] = ok ? s : w;
        wts[u] = ok ? __uint_as_float(wb) : 0.f;
      }
      uint32_t hh[8];
      #pragma unroll
      for (int u = 0; u < 8; ++u) hh[u] = H1[(size_t)ss[u]*64 + lane];
      #pragma unroll
      for (int u = 0; u < 8; ++u){
        a0 = fmaf(wts[u], bflo(hh[u]), a0);
        a1 = fmaf(wts[u], bfhi(hh[u]), a1);
      }
    }
  }
  a0 += b1[lane*2]; a1 += b1[lane*2+1];
  a0 = (a0 >= 0.f) ? a0 : 0.01f * a0;
  a1 = (a1 >= 0.f) ? a1 : 0.01f * a1;
  A1[(size_t)w*64 + lane] = pack2bf(a0, a1);
}

// ---------- GEMM2 (MFMA): H2[N,64](bf16) = A1[N,128](bf16) @ bf16(W2) ----------
// A-frags load directly from global (A1 already bf16, row stride 256B).
__global__ __launch_bounds__(256) void k_gemm2_mfma(const uint4* __restrict__ A1,
    const uint4* __restrict__ W2f, unsigned short* __restrict__ H2, int n){
  int wv = (int)((blockIdx.x * 256u + threadIdx.x) >> 6);
  int lane = threadIdx.x & 63;
  int row0 = wv * 32;
  if (row0 >= n) return;
  int rA = lane & 15, kg = lane >> 4;
  f32x4 acc[2][4];
  #pragma unroll
  for (int mt = 0; mt < 2; ++mt)
    #pragma unroll
    for (int nt = 0; nt < 4; ++nt) acc[mt][nt] = (f32x4){0.f, 0.f, 0.f, 0.f};
  int r0 = min(row0 + rA,      n - 1);
  int r1 = min(row0 + 16 + rA, n - 1);
  #pragma unroll
  for (int ks = 0; ks < 4; ++ks){
    U4S8 a0, a1;
    a0.u = A1[(size_t)r0*16 + ks*4 + kg];
    a1.u = A1[(size_t)r1*16 + ks*4 + kg];
    #pragma unroll
    for (int nt = 0; nt < 4; ++nt){
      U4S8 b; b.u = W2f[(ks*4 + nt)*64 + lane];
      acc[0][nt] = __builtin_amdgcn_mfma_f32_16x16x32_bf16(a0.s, b.s, acc[0][nt], 0, 0, 0);
      acc[1][nt] = __builtin_amdgcn_mfma_f32_16x16x32_bf16(a1.s, b.s, acc[1][nt], 0, 0, 0);
    }
  }
  #pragma unroll
  for (int mt = 0; mt < 2; ++mt){
    #pragma unroll
    for (int r = 0; r < 4; ++r){
      int row = row0 + mt*16 + kg*4 + r;
      if (row < n){
        #pragma unroll
        for (int nt = 0; nt < 4; ++nt)
          H2[(size_t)row*64 + nt*16 + rA] = (unsigned short)f2bf_bits(acc[mt][nt][r]);
      }
    }
  }
}

// ---------- agg2: out = Ahat @ H2 + b2  (f32 out) ----------
__global__ __launch_bounds__(256) void k_agg2(const unsigned short* __restrict__ H2,
    const int2* __restrict__ edges,
    const int* __restrict__ start, const int* __restrict__ cnt,
    const float* __restrict__ dinv, const float* __restrict__ b2,
    float* __restrict__ out, int n){
  int w = (int)((blockIdx.x * blockDim.x + threadIdx.x) >> 6);
  int lane = threadIdx.x & 63;
  if (w >= n) return;
  float di = dinv[w];
  float a = di * di * __uint_as_float(((uint32_t)H2[(size_t)w*64 + lane]) << 16);
  int e0 = start[w], deg = cnt[w];
  for (int base = 0; base < deg; base += 64){
    int nin = min(64, deg - base);
    int2 ew = (lane < nin) ? edges[e0 + base + lane] : make_int2(0, 0);
    for (int j = 0; j < nin; j += 8){
      int ss[8]; float wts[8];
      #pragma unroll
      for (int u = 0; u < 8; ++u){
        int jj = j + u;
        int s = __shfl(ew.x, jj & 63);
        uint32_t wb = (uint32_t)__shfl(ew.y, jj & 63);
        bool ok = jj < nin;
        ss[u] = ok ? s : w;
        wts[u] = ok ? __uint_as_float(wb) : 0.f;
      }
      unsigned short hh[8];
      #pragma unroll
      for (int u = 0; u < 8; ++u) hh[u] = H2[(size_t)ss[u]*64 + lane];
      #pragma unroll
      for (int u = 0; u < 8; ++u)
        a = fmaf(wts[u], __uint_as_float(((uint32_t)hh[u]) << 16), a);
    }
  }
  out[(size_t)w*64 + lane] = a + b2[lane];
}

extern "C" void kernel_launch(void* const* d_in, const int* in_sizes, int n_in,
                              void* d_out, int out_size, void* d_ws, size_t ws_size,
                              hipStream_t stream){
  const float* x  = (const float*)d_in[0];
  const int*   ei = (const int*)d_in[1];   // [2,E] int32
  const float* W1 = (const float*)d_in[2];
  const float* b1 = (const float*)d_in[3];
  const float* W2 = (const float*)d_in[4];
  const float* b2 = (const float*)d_in[5];
  float* out = (float*)d_out;

  int N = in_sizes[0] / 256;
  int E = in_sizes[1] / 2;

  char* p = (char*)d_ws;
  uint32_t* H1 = (uint32_t*)p;  p += (size_t)N*64*4;   // [N,128] bf16
  uint32_t* A1 = (uint32_t*)p;  p += (size_t)N*64*4;   // [N,128] bf16
  uint32_t* H2 = (uint32_t*)p;  p += (size_t)N*32*4;   // [N,64]  bf16
  int2* edges  = (int2*)p;      p += (size_t)E*8;      // packed (src, w)
  uint4* W1f   = (uint4*)p;     p += 8*8*64*16;        // W1 bf16 frags (64 KB)
  uint4* W2f   = (uint4*)p;     p += 4*4*64*16;        // W2 bf16 frags (16 KB)
  int* cnt     = (int*)p;       p += (size_t)N*4;      // | contiguous zero region:
  int* fillpos = (int*)p;       p += (size_t)N*4;      // | cnt, fillpos, counter
  int* counter = (int*)p;       p += 16;               // |
  int* start   = (int*)p;       p += (size_t)N*4;
  float* dinv  = (float*)p;     p += (size_t)N*4;

  hipMemsetAsync(cnt, 0, (size_t)(2*N)*4 + 16, stream);

  const int* srcIdx = ei;
  const int* dstIdx = ei + E;

  int nWaveBlocks = ((N + 31)/32 + 3) / 4;   // 1 wave per 32 rows, 4 waves/block

  k_packW<<<(8*8*64 + 255)/256, 256, 0, stream>>>(W1, W1f, 256, 128);
  k_packW<<<(4*4*64 + 255)/256, 256, 0, stream>>>(W2, W2f, 128, 64);
  k_count<<<(E+255)/256, 256, 0, stream>>>(dstIdx, E, cnt);
  k_dinv_start<<<(N+255)/256, 256, 0, stream>>>(cnt, dinv, start, counter, N);
  k_fill<<<(E+255)/256, 256, 0, stream>>>(srcIdx, dstIdx, E, dinv, start, fillpos, edges);
  k_gemm1_mfma<<<nWaveBlocks, 256, 0, stream>>>(x, W1f, (unsigned short*)H1, N);
  k_agg1<<<(N+3)/4, 256, 0, stream>>>(H1, edges, start, cnt, dinv, b1, A1, N);
  k_gemm2_mfma<<<nWaveBlocks, 256, 0, stream>>>((const uint4*)A1, W2f, (unsigned short*)H2, N);
  k_agg2<<<(N+3)/4, 256, 0, stream>>>((const unsigned short*)H2, edges, start, cnt, dinv, b2, out, N);
}

// Round 4
// 236.926 us; speedup vs baseline: 2.6852x; 1.4973x over previous
//
#include <hip/hip_runtime.h>
#include <hip/hip_bf16.h>
#include <stdint.h>

#define GPART 512      // partition grid blocks
#define BSHIFT 9
#define BSIZE 512      // nodes per bucket
#define MAXNB 512      // LDS histogram capacity (N up to 262144)

typedef short short8 __attribute__((ext_vector_type(8)));
typedef float f32x4 __attribute__((ext_vector_type(4)));
union U4S8 { uint4 u; short8 s; };

// ---------- bf16 helpers (raw-bits; RNE pack) ----------
static __device__ __forceinline__ float bflo(uint32_t h){ return __uint_as_float(h << 16); }
static __device__ __forceinline__ float bfhi(uint32_t h){ return __uint_as_float(h & 0xFFFF0000u); }
static __device__ __forceinline__ uint32_t f2bf_bits(float f){
  uint32_t u = __float_as_uint(f);
  return (u + 0x7FFFu + ((u >> 16) & 1u)) >> 16;
}
static __device__ __forceinline__ uint32_t pack2bf(float lo, float hi){
  return f2bf_bits(lo) | (f2bf_bits(hi) << 16);
}

// ---------- partition pass 1: per-(block,bucket) histogram ----------
__global__ __launch_bounds__(256) void k_hist(const int* __restrict__ dst, int E, int NB,
    int* __restrict__ gHist){
  __shared__ int lh[MAXNB];
  int blk = blockIdx.x;
  for (int i = threadIdx.x; i < NB; i += 256) lh[i] = 0;
  __syncthreads();
  int chunk = (E + GPART - 1) / GPART;
  int e0 = blk * chunk, e1 = min(E, e0 + chunk);
  for (int e = e0 + threadIdx.x; e < e1; e += 256)
    atomicAdd(&lh[dst[e] >> BSHIFT], 1);
  __syncthreads();
  for (int i = threadIdx.x; i < NB; i += 256) gHist[i * GPART + blk] = lh[i];
}

// ---------- partition pass 2a: scan block counts within each bucket ----------
__global__ __launch_bounds__(64) void k_scanA(int* __restrict__ gHist,
    int* __restrict__ bucketTotal){
  int b = blockIdx.x;
  int lane = threadIdx.x;
  int carry = 0;
  #pragma unroll
  for (int r = 0; r < GPART/64; ++r){
    int v = gHist[b*GPART + r*64 + lane];
    int pref = v;
    #pragma unroll
    for (int off = 1; off < 64; off <<= 1){ int t = __shfl_up(pref, off); if (lane >= off) pref += t; }
    int tot = __shfl(pref, 63);
    gHist[b*GPART + r*64 + lane] = carry + pref - v;
    carry += tot;
  }
  if (lane == 0) bucketTotal[b] = carry;
}

// ---------- partition pass 2b: exclusive scan of bucket totals ----------
__global__ __launch_bounds__(64) void k_scanB(const int* __restrict__ bucketTotal, int NB,
    int* __restrict__ bucketBase){
  int lane = threadIdx.x;
  int carry = 0;
  for (int r = 0; r*64 < NB; ++r){
    int idx = r*64 + lane;
    int v = (idx < NB) ? bucketTotal[idx] : 0;
    int pref = v;
    #pragma unroll
    for (int off = 1; off < 64; off <<= 1){ int t = __shfl_up(pref, off); if (lane >= off) pref += t; }
    int tot = __shfl(pref, 63);
    if (idx < NB) bucketBase[idx] = carry + pref - v;
    carry += tot;
  }
}

// ---------- partition pass 3: scatter into bucket-grouped edge array ----------
// entry = src | (d & 511) << 23   (src < 2^23)
__global__ __launch_bounds__(256) void k_scatter(const int* __restrict__ src,
    const int* __restrict__ dst, int E, int NB,
    const int* __restrict__ gHist, const int* __restrict__ bucketBase,
    uint32_t* __restrict__ edgesP){
  __shared__ int lpos[MAXNB];
  int blk = blockIdx.x;
  for (int i = threadIdx.x; i < NB; i += 256) lpos[i] = 0;
  __syncthreads();
  int chunk = (E + GPART - 1) / GPART;
  int e0 = blk * chunk, e1 = min(E, e0 + chunk);
  for (int e = e0 + threadIdx.x; e < e1; e += 256){
    int s = src[e], d = dst[e];
    int b = d >> BSHIFT;
    int o = atomicAdd(&lpos[b], 1);
    int pos = bucketBase[b] + gHist[b*GPART + blk] + o;
    edgesP[pos] = (uint32_t)s | ((uint32_t)(d & (BSIZE-1)) << 23);
  }
}

// ---------- CSR build: one block per bucket, all-local two-pass ----------
__global__ __launch_bounds__(256) void k_buildcsr(const uint32_t* __restrict__ edgesP,
    const int* __restrict__ bucketBase, const int* __restrict__ bucketTotal,
    int n, int* __restrict__ start, int* __restrict__ cnt, float* __restrict__ dinv,
    int* __restrict__ csr){
  __shared__ int cnt_l[BSIZE], start_l[BSIZE], fp[BSIZE];
  int b = blockIdx.x;
  int base = bucketBase[b], total = bucketTotal[b];
  int d0 = b << BSHIFT;
  int tid = threadIdx.x;
  for (int i = tid; i < BSIZE; i += 256){ cnt_l[i] = 0; fp[i] = 0; }
  __syncthreads();
  for (int i = tid; i < total; i += 256)
    atomicAdd(&cnt_l[edgesP[base + i] >> 23], 1);
  __syncthreads();
  if (tid < 64){
    int lane = tid, carry = 0;
    #pragma unroll
    for (int r = 0; r < BSIZE/64; ++r){
      int v = cnt_l[r*64 + lane];
      int pref = v;
      #pragma unroll
      for (int off = 1; off < 64; off <<= 1){ int t = __shfl_up(pref, off); if (lane >= off) pref += t; }
      int tot = __shfl(pref, 63);
      start_l[r*64 + lane] = carry + pref - v;
      carry += tot;
    }
  }
  __syncthreads();
  for (int i = tid; i < BSIZE; i += 256){
    int d = d0 + i;
    if (d < n){
      int c = cnt_l[i];
      cnt[d] = c;
      start[d] = base + start_l[i];
      dinv[d] = rsqrtf((float)(c + 1));
    }
  }
  for (int i = tid; i < total; i += 256){
    uint32_t w = edgesP[base + i];
    int dl = (int)(w >> 23);
    int s = (int)(w & 0x7FFFFFu);
    int p = atomicAdd(&fp[dl], 1);
    csr[base + start_l[dl] + p] = s;
  }
}

// ---------- weight pre-pack: W[K][Nc] f32 -> bf16 MFMA B-fragments ----------
__global__ __launch_bounds__(256) void k_packW(const float* __restrict__ W,
    uint4* __restrict__ Wf, int K, int Nc){
  int s = blockIdx.x * 256 + threadIdx.x;
  int total = (K >> 5) * (Nc >> 4) * 64;
  if (s >= total) return;
  int lane = s & 63;
  int frag = s >> 6;
  int NT = Nc >> 4;
  int nt = frag % NT, ks = frag / NT;
  int col = nt*16 + (lane & 15);
  int k0  = ks*32 + (lane >> 4)*8;
  float v[8];
  #pragma unroll
  for (int e = 0; e < 8; ++e) v[e] = W[(size_t)(k0 + e)*Nc + col];
  uint4 u;
  u.x = pack2bf(v[0], v[1]); u.y = pack2bf(v[2], v[3]);
  u.z = pack2bf(v[4], v[5]); u.w = pack2bf(v[6], v[7]);
  Wf[s] = u;
}

// ---------- GEMM1 (MFMA): H1[N,128](bf16) = bf16(X[N,256]) @ bf16(W1) ----------
__global__ __launch_bounds__(256) void k_gemm1_mfma(const float* __restrict__ X,
    const uint4* __restrict__ W1f, unsigned short* __restrict__ H1, int n){
  int wv = (int)((blockIdx.x * 256u + threadIdx.x) >> 6);
  int lane = threadIdx.x & 63;
  int row0 = wv * 32;
  if (row0 >= n) return;
  int rA = lane & 15, kg = lane >> 4;
  f32x4 acc[2][8];
  #pragma unroll
  for (int mt = 0; mt < 2; ++mt)
    #pragma unroll
    for (int nt = 0; nt < 8; ++nt) acc[mt][nt] = (f32x4){0.f, 0.f, 0.f, 0.f};
  int r0 = min(row0 + rA,      n - 1);
  int r1 = min(row0 + 16 + rA, n - 1);
  const float* x0 = X + (size_t)r0*256 + kg*8;
  const float* x1 = X + (size_t)r1*256 + kg*8;
  for (int ks = 0; ks < 8; ++ks){
    U4S8 a0, a1; float4 f;
    f = *(const float4*)(x0 + ks*32);     a0.u.x = pack2bf(f.x,f.y); a0.u.y = pack2bf(f.z,f.w);
    f = *(const float4*)(x0 + ks*32 + 4); a0.u.z = pack2bf(f.x,f.y); a0.u.w = pack2bf(f.z,f.w);
    f = *(const float4*)(x1 + ks*32);     a1.u.x = pack2bf(f.x,f.y); a1.u.y = pack2bf(f.z,f.w);
    f = *(const float4*)(x1 + ks*32 + 4); a1.u.z = pack2bf(f.x,f.y); a1.u.w = pack2bf(f.z,f.w);
    #pragma unroll
    for (int nt = 0; nt < 8; ++nt){
      U4S8 b; b.u = W1f[(ks*8 + nt)*64 + lane];
      acc[0][nt] = __builtin_amdgcn_mfma_f32_16x16x32_bf16(a0.s, b.s, acc[0][nt], 0, 0, 0);
      acc[1][nt] = __builtin_amdgcn_mfma_f32_16x16x32_bf16(a1.s, b.s, acc[1][nt], 0, 0, 0);
    }
  }
  #pragma unroll
  for (int mt = 0; mt < 2; ++mt){
    #pragma unroll
    for (int r = 0; r < 4; ++r){
      int row = row0 + mt*16 + kg*4 + r;
      if (row < n){
        #pragma unroll
        for (int nt = 0; nt < 8; ++nt)
          H1[(size_t)row*128 + nt*16 + rA] = (unsigned short)f2bf_bits(acc[mt][nt][r]);
      }
    }
  }
}

// ---------- agg1: A1 = leakyrelu(Ahat @ H1 + b1)  (bf16 out) ----------
// csr stores src only; weight = dinv[src]*dinv[w] computed here.
__global__ __launch_bounds__(256) void k_agg1(const uint32_t* __restrict__ H1,
    const int* __restrict__ csr,
    const int* __restrict__ start, const int* __restrict__ cnt,
    const float* __restrict__ dinv, const float* __restrict__ b1,
    uint32_t* __restrict__ A1, int n){
  int w = (int)((blockIdx.x * blockDim.x + threadIdx.x) >> 6);
  int lane = threadIdx.x & 63;
  if (w >= n) return;
  float dw = dinv[w];
  uint32_t h = H1[(size_t)w*64 + lane];
  float sw = dw * dw;                 // self-loop weight
  float a0 = sw * bflo(h), a1 = sw * bfhi(h);
  int e0 = start[w], deg = cnt[w];
  for (int base = 0; base < deg; base += 64){
    int nin = min(64, deg - base);
    int sE = (lane < nin) ? csr[e0 + base + lane] : 0;
    float dvE = (lane < nin) ? dinv[sE] : 0.f;
    for (int j = 0; j < nin; j += 8){
      int ss[8]; float wts[8];
      #pragma unroll
      for (int u = 0; u < 8; ++u){
        int jj = j + u;
        int s = __shfl(sE, jj & 63);
        float dv = __shfl(dvE, jj & 63);
        bool ok = jj < nin;
        ss[u] = ok ? s : w;
        wts[u] = ok ? dv * dw : 0.f;
      }
      uint32_t hh[8];
      #pragma unroll
      for (int u = 0; u < 8; ++u) hh[u] = H1[(size_t)ss[u]*64 + lane];
      #pragma unroll
      for (int u = 0; u < 8; ++u){
        a0 = fmaf(wts[u], bflo(hh[u]), a0);
        a1 = fmaf(wts[u], bfhi(hh[u]), a1);
      }
    }
  }
  a0 += b1[lane*2]; a1 += b1[lane*2+1];
  a0 = (a0 >= 0.f) ? a0 : 0.01f * a0;
  a1 = (a1 >= 0.f) ? a1 : 0.01f * a1;
  A1[(size_t)w*64 + lane] = pack2bf(a0, a1);
}

// ---------- GEMM2 (MFMA): H2[N,64](bf16) = A1[N,128](bf16) @ bf16(W2) ----------
__global__ __launch_bounds__(256) void k_gemm2_mfma(const uint4* __restrict__ A1,
    const uint4* __restrict__ W2f, unsigned short* __restrict__ H2, int n){
  int wv = (int)((blockIdx.x * 256u + threadIdx.x) >> 6);
  int lane = threadIdx.x & 63;
  int row0 = wv * 32;
  if (row0 >= n) return;
  int rA = lane & 15, kg = lane >> 4;
  f32x4 acc[2][4];
  #pragma unroll
  for (int mt = 0; mt < 2; ++mt)
    #pragma unroll
    for (int nt = 0; nt < 4; ++nt) acc[mt][nt] = (f32x4){0.f, 0.f, 0.f, 0.f};
  int r0 = min(row0 + rA,      n - 1);
  int r1 = min(row0 + 16 + rA, n - 1);
  #pragma unroll
  for (int ks = 0; ks < 4; ++ks){
    U4S8 a0, a1;
    a0.u = A1[(size_t)r0*16 + ks*4 + kg];
    a1.u = A1[(size_t)r1*16 + ks*4 + kg];
    #pragma unroll
    for (int nt = 0; nt < 4; ++nt){
      U4S8 b; b.u = W2f[(ks*4 + nt)*64 + lane];
      acc[0][nt] = __builtin_amdgcn_mfma_f32_16x16x32_bf16(a0.s, b.s, acc[0][nt], 0, 0, 0);
      acc[1][nt] = __builtin_amdgcn_mfma_f32_16x16x32_bf16(a1.s, b.s, acc[1][nt], 0, 0, 0);
    }
  }
  #pragma unroll
  for (int mt = 0; mt < 2; ++mt){
    #pragma unroll
    for (int r = 0; r < 4; ++r){
      int row = row0 + mt*16 + kg*4 + r;
      if (row < n){
        #pragma unroll
        for (int nt = 0; nt < 4; ++nt)
          H2[(size_t)row*64 + nt*16 + rA] = (unsigned short)f2bf_bits(acc[mt][nt][r]);
      }
    }
  }
}

// ---------- agg2: out = Ahat @ H2 + b2  (f32 out) ----------
__global__ __launch_bounds__(256) void k_agg2(const unsigned short* __restrict__ H2,
    const int* __restrict__ csr,
    const int* __restrict__ start, const int* __restrict__ cnt,
    const float* __restrict__ dinv, const float* __restrict__ b2,
    float* __restrict__ out, int n){
  int w = (int)((blockIdx.x * blockDim.x + threadIdx.x) >> 6);
  int lane = threadIdx.x & 63;
  if (w >= n) return;
  float dw = dinv[w];
  float a = dw * dw * __uint_as_float(((uint32_t)H2[(size_t)w*64 + lane]) << 16);
  int e0 = start[w], deg = cnt[w];
  for (int base = 0; base < deg; base += 64){
    int nin = min(64, deg - base);
    int sE = (lane < nin) ? csr[e0 + base + lane] : 0;
    float dvE = (lane < nin) ? dinv[sE] : 0.f;
    for (int j = 0; j < nin; j += 8){
      int ss[8]; float wts[8];
      #pragma unroll
      for (int u = 0; u < 8; ++u){
        int jj = j + u;
        int s = __shfl(sE, jj & 63);
        float dv = __shfl(dvE, jj & 63);
        bool ok = jj < nin;
        ss[u] = ok ? s : w;
        wts[u] = ok ? dv * dw : 0.f;
      }
      unsigned short hh[8];
      #pragma unroll
      for (int u = 0; u < 8; ++u) hh[u] = H2[(size_t)ss[u]*64 + lane];
      #pragma unroll
      for (int u = 0; u < 8; ++u)
        a = fmaf(wts[u], __uint_as_float(((uint32_t)hh[u]) << 16), a);
    }
  }
  out[(size_t)w*64 + lane] = a + b2[lane];
}

extern "C" void kernel_launch(void* const* d_in, const int* in_sizes, int n_in,
                              void* d_out, int out_size, void* d_ws, size_t ws_size,
                              hipStream_t stream){
  const float* x  = (const float*)d_in[0];
  const int*   ei = (const int*)d_in[1];   // [2,E] int32
  const float* W1 = (const float*)d_in[2];
  const float* b1 = (const float*)d_in[3];
  const float* W2 = (const float*)d_in[4];
  const float* b2 = (const float*)d_in[5];
  float* out = (float*)d_out;

  int N = in_sizes[0] / 256;
  int E = in_sizes[1] / 2;
  int NB = (N + BSIZE - 1) >> BSHIFT;

  char* p = (char*)d_ws;
  uint32_t* H1   = (uint32_t*)p;  p += (size_t)N*64*4;    // [N,128] bf16
  uint32_t* A1   = (uint32_t*)p;  p += (size_t)N*64*4;    // [N,128] bf16
  uint32_t* H2   = (uint32_t*)p;  p += (size_t)N*32*4;    // [N,64]  bf16
  uint32_t* edgesP=(uint32_t*)p;  p += (size_t)E*4;       // bucket-grouped edges
  int* csr       = (int*)p;       p += (size_t)E*4;       // src-only CSR
  int* gHist     = (int*)p;       p += (size_t)NB*GPART*4;
  int* bucketTotal=(int*)p;       p += (size_t)((NB+63)&~63)*4;
  int* bucketBase= (int*)p;       p += (size_t)((NB+63)&~63)*4;
  uint4* W1f     = (uint4*)p;     p += 8*8*64*16;         // 64 KB
  uint4* W2f     = (uint4*)p;     p += 4*4*64*16;         // 16 KB
  int* start     = (int*)p;       p += (size_t)N*4;
  int* cnt       = (int*)p;       p += (size_t)N*4;
  float* dinv    = (float*)p;     p += (size_t)N*4;

  const int* srcIdx = ei;
  const int* dstIdx = ei + E;

  int nWaveBlocks = ((N + 31)/32 + 3) / 4;   // 1 wave per 32 rows, 4 waves/block

  k_packW<<<(8*8*64 + 255)/256, 256, 0, stream>>>(W1, W1f, 256, 128);
  k_packW<<<(4*4*64 + 255)/256, 256, 0, stream>>>(W2, W2f, 128, 64);
  k_hist<<<GPART, 256, 0, stream>>>(dstIdx, E, NB, gHist);
  k_scanA<<<NB, 64, 0, stream>>>(gHist, bucketTotal);
  k_scanB<<<1, 64, 0, stream>>>(bucketTotal, NB, bucketBase);
  k_scatter<<<GPART, 256, 0, stream>>>(srcIdx, dstIdx, E, NB, gHist, bucketBase, edgesP);
  k_buildcsr<<<NB, 256, 0, stream>>>(edgesP, bucketBase, bucketTotal, N, start, cnt, dinv, csr);
  k_gemm1_mfma<<<nWaveBlocks, 256, 0, stream>>>(x, W1f, (unsigned short*)H1, N);
  k_agg1<<<(N+3)/4, 256, 0, stream>>>(H1, csr, start, cnt, dinv, b1, A1, N);
  k_gemm2_mfma<<<nWaveBlocks, 256, 0, stream>>>((const uint4*)A1, W2f, (unsigned short*)H2, N);
  k_agg2<<<(N+3)/4, 256, 0, stream>>>((const unsigned short*)H2, csr, start, cnt, dinv, b2, out, N);
}

// Round 5
// 213.957 us; speedup vs baseline: 2.9735x; 1.1074x over previous
//
#include <hip/hip_runtime.h>
#include <hip/hip_bf16.h>
#include <stdint.h>

#define GPART 512      // partition grid blocks
#define BSHIFT 9
#define BSIZE 512      // nodes per bucket
#define MAXNB 512      // LDS histogram capacity (N up to 262144)

typedef short short8 __attribute__((ext_vector_type(8)));
typedef float f32x4 __attribute__((ext_vector_type(4)));
union U4S8 { uint4 u; short8 s; };

// ---------- bf16 helpers (raw-bits; RNE pack) ----------
static __device__ __forceinline__ float bflo(uint32_t h){ return __uint_as_float(h << 16); }
static __device__ __forceinline__ float bfhi(uint32_t h){ return __uint_as_float(h & 0xFFFF0000u); }
static __device__ __forceinline__ uint32_t f2bf_bits(float f){
  uint32_t u = __float_as_uint(f);
  return (u + 0x7FFFu + ((u >> 16) & 1u)) >> 16;
}
static __device__ __forceinline__ uint32_t pack2bf(float lo, float hi){
  return f2bf_bits(lo) | (f2bf_bits(hi) << 16);
}

// ---------- partition pass 1: per-(block,bucket) histogram ----------
__global__ __launch_bounds__(256) void k_hist(const int* __restrict__ dst, int E, int NB,
    int* __restrict__ gHist){
  __shared__ int lh[MAXNB];
  int blk = blockIdx.x;
  for (int i = threadIdx.x; i < NB; i += 256) lh[i] = 0;
  __syncthreads();
  int chunk = (E + GPART - 1) / GPART;
  int e0 = blk * chunk, e1 = min(E, e0 + chunk);
  for (int e = e0 + threadIdx.x; e < e1; e += 256)
    atomicAdd(&lh[dst[e] >> BSHIFT], 1);
  __syncthreads();
  for (int i = threadIdx.x; i < NB; i += 256) gHist[i * GPART + blk] = lh[i];
}

// ---------- partition pass 2a: scan block counts within each bucket ----------
__global__ __launch_bounds__(64) void k_scanA(int* __restrict__ gHist,
    int* __restrict__ bucketTotal){
  int b = blockIdx.x;
  int lane = threadIdx.x;
  int carry = 0;
  #pragma unroll
  for (int r = 0; r < GPART/64; ++r){
    int v = gHist[b*GPART + r*64 + lane];
    int pref = v;
    #pragma unroll
    for (int off = 1; off < 64; off <<= 1){ int t = __shfl_up(pref, off); if (lane >= off) pref += t; }
    int tot = __shfl(pref, 63);
    gHist[b*GPART + r*64 + lane] = carry + pref - v;
    carry += tot;
  }
  if (lane == 0) bucketTotal[b] = carry;
}

// ---------- partition pass 2b: exclusive scan of bucket totals ----------
__global__ __launch_bounds__(64) void k_scanB(const int* __restrict__ bucketTotal, int NB,
    int* __restrict__ bucketBase){
  int lane = threadIdx.x;
  int carry = 0;
  for (int r = 0; r*64 < NB; ++r){
    int idx = r*64 + lane;
    int v = (idx < NB) ? bucketTotal[idx] : 0;
    int pref = v;
    #pragma unroll
    for (int off = 1; off < 64; off <<= 1){ int t = __shfl_up(pref, off); if (lane >= off) pref += t; }
    int tot = __shfl(pref, 63);
    if (idx < NB) bucketBase[idx] = carry + pref - v;
    carry += tot;
  }
}

// ---------- partition pass 3: scatter into bucket-grouped edge array ----------
// entry = src | (d & 511) << 23   (src < 2^23)
__global__ __launch_bounds__(256) void k_scatter(const int* __restrict__ src,
    const int* __restrict__ dst, int E, int NB,
    const int* __restrict__ gHist, const int* __restrict__ bucketBase,
    uint32_t* __restrict__ edgesP){
  __shared__ int lpos[MAXNB];
  int blk = blockIdx.x;
  for (int i = threadIdx.x; i < NB; i += 256) lpos[i] = 0;
  __syncthreads();
  int chunk = (E + GPART - 1) / GPART;
  int e0 = blk * chunk, e1 = min(E, e0 + chunk);
  for (int e = e0 + threadIdx.x; e < e1; e += 256){
    int s = src[e], d = dst[e];
    int b = d >> BSHIFT;
    int o = atomicAdd(&lpos[b], 1);
    int pos = bucketBase[b] + gHist[b*GPART + blk] + o;
    edgesP[pos] = (uint32_t)s | ((uint32_t)(d & (BSIZE-1)) << 23);
  }
}

// ---------- CSR build: one block per bucket, all-local two-pass ----------
__global__ __launch_bounds__(256) void k_buildcsr(const uint32_t* __restrict__ edgesP,
    const int* __restrict__ bucketBase, const int* __restrict__ bucketTotal,
    int n, int* __restrict__ start, int* __restrict__ cnt, float* __restrict__ dinv,
    int* __restrict__ csr){
  __shared__ int cnt_l[BSIZE], start_l[BSIZE], fp[BSIZE];
  int b = blockIdx.x;
  int base = bucketBase[b], total = bucketTotal[b];
  int d0 = b << BSHIFT;
  int tid = threadIdx.x;
  for (int i = tid; i < BSIZE; i += 256){ cnt_l[i] = 0; fp[i] = 0; }
  __syncthreads();
  for (int i = tid; i < total; i += 256)
    atomicAdd(&cnt_l[edgesP[base + i] >> 23], 1);
  __syncthreads();
  if (tid < 64){
    int lane = tid, carry = 0;
    #pragma unroll
    for (int r = 0; r < BSIZE/64; ++r){
      int v = cnt_l[r*64 + lane];
      int pref = v;
      #pragma unroll
      for (int off = 1; off < 64; off <<= 1){ int t = __shfl_up(pref, off); if (lane >= off) pref += t; }
      int tot = __shfl(pref, 63);
      start_l[r*64 + lane] = carry + pref - v;
      carry += tot;
    }
  }
  __syncthreads();
  for (int i = tid; i < BSIZE; i += 256){
    int d = d0 + i;
    if (d < n){
      int c = cnt_l[i];
      cnt[d] = c;
      start[d] = base + start_l[i];
      dinv[d] = rsqrtf((float)(c + 1));
    }
  }
  for (int i = tid; i < total; i += 256){
    uint32_t w = edgesP[base + i];
    int dl = (int)(w >> 23);
    int s = (int)(w & 0x7FFFFFu);
    int p = atomicAdd(&fp[dl], 1);
    csr[base + start_l[dl] + p] = s;
  }
}

// ---------- weight pre-pack: W[K][Nc] f32 -> bf16 MFMA B-fragments ----------
__global__ __launch_bounds__(256) void k_packW(const float* __restrict__ W,
    uint4* __restrict__ Wf, int K, int Nc){
  int s = blockIdx.x * 256 + threadIdx.x;
  int total = (K >> 5) * (Nc >> 4) * 64;
  if (s >= total) return;
  int lane = s & 63;
  int frag = s >> 6;
  int NT = Nc >> 4;
  int nt = frag % NT, ks = frag / NT;
  int col = nt*16 + (lane & 15);
  int k0  = ks*32 + (lane >> 4)*8;
  float v[8];
  #pragma unroll
  for (int e = 0; e < 8; ++e) v[e] = W[(size_t)(k0 + e)*Nc + col];
  uint4 u;
  u.x = pack2bf(v[0], v[1]); u.y = pack2bf(v[2], v[3]);
  u.z = pack2bf(v[4], v[5]); u.w = pack2bf(v[6], v[7]);
  Wf[s] = u;
}

// ---------- GEMM1 (MFMA): H1[N,128](bf16) = bf16(X[N,256]) @ bf16(W1) ----------
// one wave per 16 rows; low-VGPR; 2-stage register prefetch of X.
__global__ __launch_bounds__(256) void k_gemm1_mfma(const float* __restrict__ X,
    const uint4* __restrict__ W1f, unsigned short* __restrict__ H1, int n){
  int wv = (int)((blockIdx.x * 256u + threadIdx.x) >> 6);
  int lane = threadIdx.x & 63;
  int row0 = wv * 16;
  if (row0 >= n) return;
  int rA = lane & 15, kg = lane >> 4;
  f32x4 acc[8];
  #pragma unroll
  for (int nt = 0; nt < 8; ++nt) acc[nt] = (f32x4){0.f, 0.f, 0.f, 0.f};
  int r0 = min(row0 + rA, n - 1);
  const float* x0 = X + (size_t)r0*256 + kg*8;
  float4 fa = *(const float4*)(x0);
  float4 fb = *(const float4*)(x0 + 4);
  for (int ks = 0; ks < 8; ++ks){
    U4S8 a;
    a.u.x = pack2bf(fa.x, fa.y); a.u.y = pack2bf(fa.z, fa.w);
    a.u.z = pack2bf(fb.x, fb.y); a.u.w = pack2bf(fb.z, fb.w);
    if (ks < 7){
      fa = *(const float4*)(x0 + (ks+1)*32);
      fb = *(const float4*)(x0 + (ks+1)*32 + 4);
    }
    #pragma unroll
    for (int nt = 0; nt < 8; ++nt){
      U4S8 b; b.u = W1f[(ks*8 + nt)*64 + lane];
      acc[nt] = __builtin_amdgcn_mfma_f32_16x16x32_bf16(a.s, b.s, acc[nt], 0, 0, 0);
    }
  }
  #pragma unroll
  for (int r = 0; r < 4; ++r){
    int row = row0 + kg*4 + r;
    if (row < n){
      #pragma unroll
      for (int nt = 0; nt < 8; ++nt)
        H1[(size_t)row*128 + nt*16 + rA] = (unsigned short)f2bf_bits(acc[nt][r]);
    }
  }
}

// ---------- agg1: A1 = leakyrelu(Ahat @ H1 + b1)  (bf16 out) ----------
// csr stores src only; weight = dinv[src]*dinv[w] computed here.
__global__ __launch_bounds__(256) void k_agg1(const uint32_t* __restrict__ H1,
    const int* __restrict__ csr,
    const int* __restrict__ start, const int* __restrict__ cnt,
    const float* __restrict__ dinv, const float* __restrict__ b1,
    uint32_t* __restrict__ A1, int n){
  int w = (int)((blockIdx.x * blockDim.x + threadIdx.x) >> 6);
  int lane = threadIdx.x & 63;
  if (w >= n) return;
  float dw = dinv[w];
  uint32_t h = H1[(size_t)w*64 + lane];
  float sw = dw * dw;                 // self-loop weight
  float a0 = sw * bflo(h), a1 = sw * bfhi(h);
  int e0 = start[w], deg = cnt[w];
  for (int base = 0; base < deg; base += 64){
    int nin = min(64, deg - base);
    int sE = (lane < nin) ? csr[e0 + base + lane] : 0;
    float dvE = (lane < nin) ? dinv[sE] : 0.f;
    for (int j = 0; j < nin; j += 8){
      int ss[8]; float wts[8];
      #pragma unroll
      for (int u = 0; u < 8; ++u){
        int jj = j + u;
        int s = __shfl(sE, jj & 63);
        float dv = __shfl(dvE, jj & 63);
        bool ok = jj < nin;
        ss[u] = ok ? s : w;
        wts[u] = ok ? dv * dw : 0.f;
      }
      uint32_t hh[8];
      #pragma unroll
      for (int u = 0; u < 8; ++u) hh[u] = H1[(size_t)ss[u]*64 + lane];
      #pragma unroll
      for (int u = 0; u < 8; ++u){
        a0 = fmaf(wts[u], bflo(hh[u]), a0);
        a1 = fmaf(wts[u], bfhi(hh[u]), a1);
      }
    }
  }
  a0 += b1[lane*2]; a1 += b1[lane*2+1];
  a0 = (a0 >= 0.f) ? a0 : 0.01f * a0;
  a1 = (a1 >= 0.f) ? a1 : 0.01f * a1;
  A1[(size_t)w*64 + lane] = pack2bf(a0, a1);
}

// ---------- GEMM2 (MFMA): H2[N,64](bf16) = A1[N,128](bf16) @ bf16(W2) ----------
// one wave per 16 rows; A-frags stream directly from global with 1-deep prefetch.
__global__ __launch_bounds__(256) void k_gemm2_mfma(const uint4* __restrict__ A1,
    const uint4* __restrict__ W2f, unsigned short* __restrict__ H2, int n){
  int wv = (int)((blockIdx.x * 256u + threadIdx.x) >> 6);
  int lane = threadIdx.x & 63;
  int row0 = wv * 16;
  if (row0 >= n) return;
  int rA = lane & 15, kg = lane >> 4;
  f32x4 acc[4];
  #pragma unroll
  for (int nt = 0; nt < 4; ++nt) acc[nt] = (f32x4){0.f, 0.f, 0.f, 0.f};
  int r0 = min(row0 + rA, n - 1);
  const uint4* arow = A1 + (size_t)r0*16 + kg;
  uint4 u = arow[0];
  #pragma unroll
  for (int ks = 0; ks < 4; ++ks){
    U4S8 a; a.u = u;
    if (ks < 3) u = arow[(ks+1)*4];
    #pragma unroll
    for (int nt = 0; nt < 4; ++nt){
      U4S8 b; b.u = W2f[(ks*4 + nt)*64 + lane];
      acc[nt] = __builtin_amdgcn_mfma_f32_16x16x32_bf16(a.s, b.s, acc[nt], 0, 0, 0);
    }
  }
  #pragma unroll
  for (int r = 0; r < 4; ++r){
    int row = row0 + kg*4 + r;
    if (row < n){
      #pragma unroll
      for (int nt = 0; nt < 4; ++nt)
        H2[(size_t)row*64 + nt*16 + rA] = (unsigned short)f2bf_bits(acc[nt][r]);
    }
  }
}

// ---------- agg2: out = Ahat @ H2 + b2  (f32 out) ----------
__global__ __launch_bounds__(256) void k_agg2(const unsigned short* __restrict__ H2,
    const int* __restrict__ csr,
    const int* __restrict__ start, const int* __restrict__ cnt,
    const float* __restrict__ dinv, const float* __restrict__ b2,
    float* __restrict__ out, int n){
  int w = (int)((blockIdx.x * blockDim.x + threadIdx.x) >> 6);
  int lane = threadIdx.x & 63;
  if (w >= n) return;
  float dw = dinv[w];
  float a = dw * dw * __uint_as_float(((uint32_t)H2[(size_t)w*64 + lane]) << 16);
  int e0 = start[w], deg = cnt[w];
  for (int base = 0; base < deg; base += 64){
    int nin = min(64, deg - base);
    int sE = (lane < nin) ? csr[e0 + base + lane] : 0;
    float dvE = (lane < nin) ? dinv[sE] : 0.f;
    for (int j = 0; j < nin; j += 8){
      int ss[8]; float wts[8];
      #pragma unroll
      for (int u = 0; u < 8; ++u){
        int jj = j + u;
        int s = __shfl(sE, jj & 63);
        float dv = __shfl(dvE, jj & 63);
        bool ok = jj < nin;
        ss[u] = ok ? s : w;
        wts[u] = ok ? dv * dw : 0.f;
      }
      unsigned short hh[8];
      #pragma unroll
      for (int u = 0; u < 8; ++u) hh[u] = H2[(size_t)ss[u]*64 + lane];
      #pragma unroll
      for (int u = 0; u < 8; ++u)
        a = fmaf(wts[u], __uint_as_float(((uint32_t)hh[u]) << 16), a);
    }
  }
  out[(size_t)w*64 + lane] = a + b2[lane];
}

extern "C" void kernel_launch(void* const* d_in, const int* in_sizes, int n_in,
                              void* d_out, int out_size, void* d_ws, size_t ws_size,
                              hipStream_t stream){
  const float* x  = (const float*)d_in[0];
  const int*   ei = (const int*)d_in[1];   // [2,E] int32
  const float* W1 = (const float*)d_in[2];
  const float* b1 = (const float*)d_in[3];
  const float* W2 = (const float*)d_in[4];
  const float* b2 = (const float*)d_in[5];
  float* out = (float*)d_out;

  int N = in_sizes[0] / 256;
  int E = in_sizes[1] / 2;
  int NB = (N + BSIZE - 1) >> BSHIFT;

  char* p = (char*)d_ws;
  uint32_t* H1   = (uint32_t*)p;  p += (size_t)N*64*4;    // [N,128] bf16
  uint32_t* A1   = (uint32_t*)p;  p += (size_t)N*64*4;    // [N,128] bf16
  uint32_t* H2   = (uint32_t*)p;  p += (size_t)N*32*4;    // [N,64]  bf16
  uint32_t* edgesP=(uint32_t*)p;  p += (size_t)E*4;       // bucket-grouped edges
  int* csr       = (int*)p;       p += (size_t)E*4;       // src-only CSR
  int* gHist     = (int*)p;       p += (size_t)NB*GPART*4;
  int* bucketTotal=(int*)p;       p += (size_t)((NB+63)&~63)*4;
  int* bucketBase= (int*)p;       p += (size_t)((NB+63)&~63)*4;
  uint4* W1f     = (uint4*)p;     p += 8*8*64*16;         // 64 KB
  uint4* W2f     = (uint4*)p;     p += 4*4*64*16;         // 16 KB
  int* start     = (int*)p;       p += (size_t)N*4;
  int* cnt       = (int*)p;       p += (size_t)N*4;
  float* dinv    = (float*)p;     p += (size_t)N*4;

  const int* srcIdx = ei;
  const int* dstIdx = ei + E;

  int nW = (N + 15) / 16;                    // 1 wave per 16 rows
  int nWaveBlocks = (nW + 3) / 4;            // 4 waves/block

  k_packW<<<(8*8*64 + 255)/256, 256, 0, stream>>>(W1, W1f, 256, 128);
  k_packW<<<(4*4*64 + 255)/256, 256, 0, stream>>>(W2, W2f, 128, 64);
  k_hist<<<GPART, 256, 0, stream>>>(dstIdx, E, NB, gHist);
  k_scanA<<<NB, 64, 0, stream>>>(gHist, bucketTotal);
  k_scanB<<<1, 64, 0, stream>>>(bucketTotal, NB, bucketBase);
  k_scatter<<<GPART, 256, 0, stream>>>(srcIdx, dstIdx, E, NB, gHist, bucketBase, edgesP);
  k_buildcsr<<<NB, 256, 0, stream>>>(edgesP, bucketBase, bucketTotal, N, start, cnt, dinv, csr);
  k_gemm1_mfma<<<nWaveBlocks, 256, 0, stream>>>(x, W1f, (unsigned short*)H1, N);
  k_agg1<<<(N+3)/4, 256, 0, stream>>>(H1, csr, start, cnt, dinv, b1, A1, N);
  k_gemm2_mfma<<<nWaveBlocks, 256, 0, stream>>>((const uint4*)A1, W2f, (unsigned short*)H2, N);
  k_agg2<<<(N+3)/4, 256, 0, stream>>>((const unsigned short*)H2, csr, start, cnt, dinv, b2, out, N);
}